// Round 2
// baseline (362.736 us; speedup 1.0000x reference)
//
#include <hip/hip_runtime.h>
#include <math.h>

// Problem shape (fixed by setup_inputs): x[64][256][56][56] fp32
constexpr int BB   = 64;
constexpr int CC   = 256;
constexpr int HW   = 3136;        // 56*56
constexpr int NV4  = HW / 4;      // 784 float4 per row
constexpr int KSEL = 128;         // C * (1 - 0.5)
#define EPSF 1e-6f

__device__ __forceinline__ float waveMax(float v) {
#pragma unroll
    for (int o = 32; o > 0; o >>= 1) v = fmaxf(v, __shfl_xor(v, o));
    return v;
}
__device__ __forceinline__ float waveSum(float v) {
#pragma unroll
    for (int o = 32; o > 0; o >>= 1) v += __shfl_xor(v, o);
    return v;
}
__device__ __forceinline__ int waveSumI(int v) {
#pragma unroll
    for (int o = 32; o > 0; o >>= 1) v += __shfl_xor(v, o);
    return v;
}

// One block per (b,c) row. Row (3136 fp32) held in registers: single HBM read.
// Exact reference semantics: p = softmax(x) + 1e-6; ent = -sum p*log(p).
__global__ __launch_bounds__(256) void ent_kernel(const float* __restrict__ x,
                                                  float* __restrict__ ent) {
    __shared__ float red[4];
    const int row = blockIdx.x;
    const float4* __restrict__ xr =
        reinterpret_cast<const float4*>(x) + (size_t)row * NV4;
    const int t = threadIdx.x;

    float4 v[4];
    float lmax = -INFINITY;
#pragma unroll
    for (int j = 0; j < 4; ++j) {
        int idx = t + j * 256;
        if (idx < NV4) {
            v[j] = xr[idx];
            lmax = fmaxf(lmax, fmaxf(fmaxf(v[j].x, v[j].y), fmaxf(v[j].z, v[j].w)));
        }
    }
    float wm = waveMax(lmax);
    if ((t & 63) == 0) red[t >> 6] = wm;
    __syncthreads();
    const float m = fmaxf(fmaxf(red[0], red[1]), fmaxf(red[2], red[3]));
    __syncthreads();

    float4 e[4];
    float lsum = 0.f;
#pragma unroll
    for (int j = 0; j < 4; ++j) {
        int idx = t + j * 256;
        if (idx < NV4) {
            e[j].x = expf(v[j].x - m);
            e[j].y = expf(v[j].y - m);
            e[j].z = expf(v[j].z - m);
            e[j].w = expf(v[j].w - m);
            lsum += (e[j].x + e[j].y) + (e[j].z + e[j].w);
        }
    }
    float ws = waveSum(lsum);
    if ((t & 63) == 0) red[t >> 6] = ws;
    __syncthreads();
    const float S = (red[0] + red[1]) + (red[2] + red[3]);
    __syncthreads();
    const float invS = 1.0f / S;

    float lent = 0.f;
#pragma unroll
    for (int j = 0; j < 4; ++j) {
        int idx = t + j * 256;
        if (idx < NV4) {
            float p0 = e[j].x * invS + EPSF;
            float p1 = e[j].y * invS + EPSF;
            float p2 = e[j].z * invS + EPSF;
            float p3 = e[j].w * invS + EPSF;
            lent += p0 * logf(p0) + p1 * logf(p1) + p2 * logf(p2) + p3 * logf(p3);
        }
    }
    float we = waveSum(lent);
    if ((t & 63) == 0) red[t >> 6] = we;
    __syncthreads();
    if (t == 0) ent[row] = -((red[0] + red[1]) + (red[2] + red[3]));
}

// One block per (b,c) row. Inline top-k rank (replicates jax.lax.top_k on
// importance=-entropy: imp_j > imp_c <=> ent_j < ent_c; ties -> lower idx),
// then copy row if kept else zero-fill. Fusing the mask step saves a launch.
__global__ __launch_bounds__(256) void apply_kernel(const float* __restrict__ x,
                                                    const float* __restrict__ ent,
                                                    float* __restrict__ out) {
    __shared__ int sred[4];
    __shared__ int skeep;
    const int row = blockIdx.x;
    const int b = row >> 8;        // row / CC
    const int c = row & (CC - 1);  // row % CC
    const int t = threadIdx.x;

    // Each thread handles one channel j=t of batch b.
    const float e_mine = ent[row];
    const float ej = ent[b * CC + t];
    int pred = (ej < e_mine) || (ej == e_mine && t < c);
    int wsum = waveSumI(pred);
    if ((t & 63) == 0) sred[t >> 6] = wsum;
    __syncthreads();
    if (t == 0) {
        int rank = (sred[0] + sred[1]) + (sred[2] + sred[3]);
        skeep = (rank < KSEL) ? 1 : 0;
    }
    __syncthreads();
    const int keep = skeep;

    const float4* __restrict__ xr =
        reinterpret_cast<const float4*>(x) + (size_t)row * NV4;
    float4* __restrict__ orow = reinterpret_cast<float4*>(out) + (size_t)row * NV4;
    if (keep) {
#pragma unroll
        for (int j = 0; j < 4; ++j) {
            int idx = t + j * 256;
            if (idx < NV4) orow[idx] = xr[idx];
        }
    } else {
        const float4 z = make_float4(0.f, 0.f, 0.f, 0.f);
#pragma unroll
        for (int j = 0; j < 4; ++j) {
            int idx = t + j * 256;
            if (idx < NV4) orow[idx] = z;
        }
    }
}

extern "C" void kernel_launch(void* const* d_in, const int* in_sizes, int n_in,
                              void* d_out, int out_size, void* d_ws, size_t ws_size,
                              hipStream_t stream) {
    const float* x = (const float*)d_in[0];
    float* out = (float*)d_out;
    float* ent = (float*)d_ws;   // 64*256*4 = 64 KiB of ws

    ent_kernel<<<BB * CC, 256, 0, stream>>>(x, ent);
    apply_kernel<<<BB * CC, 256, 0, stream>>>(x, ent, out);
}

// Round 4
// 347.361 us; speedup vs baseline: 1.0443x; 1.0443x over previous
//
#include <hip/hip_runtime.h>
#include <math.h>

// Problem shape (fixed by setup_inputs): x[64][256][56][56] fp32
constexpr int BB   = 64;
constexpr int CC   = 256;
constexpr int HW   = 3136;        // 56*56
constexpr int NV4  = HW / 4;      // 784 float4 per row
constexpr int KSEL = 128;         // C * (1 - 0.5)
#define EPSF 1e-6f

// Native clang vector type: __builtin_nontemporal_store requires it
// (HIP's float4 is a struct and is rejected).
typedef float vfloat4 __attribute__((ext_vector_type(4)));

__device__ __forceinline__ float waveMax(float v) {
#pragma unroll
    for (int o = 32; o > 0; o >>= 1) v = fmaxf(v, __shfl_xor(v, o));
    return v;
}
__device__ __forceinline__ float waveSum(float v) {
#pragma unroll
    for (int o = 32; o > 0; o >>= 1) v += __shfl_xor(v, o);
    return v;
}
__device__ __forceinline__ int waveSumI(int v) {
#pragma unroll
    for (int o = 32; o > 0; o >>= 1) v += __shfl_xor(v, o);
    return v;
}

// One block per (b,c) row; row held in registers (single HBM read).
// Entropy with the reference's +eps expanded analytically:
//   sum (p+e)ln(p+e) = [T/S - lnS] + EPS*(U - N*lnS) + N*EPS + (EPS^2/2)*S*R
// where d=x-m, e=exp(d), S=sum e, T=sum e*d, U=sum d, R=sum 1/e.
// Truncation error O(EPS^3 * sum 1/p^2) ~ 5e-9 << inter-channel gaps.
// This removes all 3136 per-row logf calls (one logf(S) remains).
__global__ __launch_bounds__(256) void ent_kernel(const float* __restrict__ x,
                                                  float* __restrict__ ent) {
    __shared__ vfloat4 red4[4];
    __shared__ float redm[4];
    const int row = blockIdx.x;
    const vfloat4* __restrict__ xr =
        reinterpret_cast<const vfloat4*>(x) + (size_t)row * NV4;
    const int t = threadIdx.x;

    vfloat4 v[4];
    float lmax = -INFINITY;
#pragma unroll
    for (int j = 0; j < 4; ++j) {
        int idx = t + j * 256;
        if (idx < NV4) {
            v[j] = xr[idx];
            lmax = fmaxf(lmax, fmaxf(fmaxf(v[j].x, v[j].y), fmaxf(v[j].z, v[j].w)));
        }
    }
    float wm = waveMax(lmax);
    if ((t & 63) == 0) redm[t >> 6] = wm;
    __syncthreads();
    const float m = fmaxf(fmaxf(redm[0], redm[1]), fmaxf(redm[2], redm[3]));

    float S = 0.f, T = 0.f, U = 0.f, R = 0.f;
#pragma unroll
    for (int j = 0; j < 4; ++j) {
        int idx = t + j * 256;
        if (idx < NV4) {
            float d0 = v[j].x - m, d1 = v[j].y - m, d2 = v[j].z - m, d3 = v[j].w - m;
            float e0 = expf(d0), e1 = expf(d1), e2 = expf(d2), e3 = expf(d3);
            S += (e0 + e1) + (e2 + e3);
            T = fmaf(e0, d0, T); T = fmaf(e1, d1, T);
            T = fmaf(e2, d2, T); T = fmaf(e3, d3, T);
            U += (d0 + d1) + (d2 + d3);
            R += (__builtin_amdgcn_rcpf(e0) + __builtin_amdgcn_rcpf(e1)) +
                 (__builtin_amdgcn_rcpf(e2) + __builtin_amdgcn_rcpf(e3));
        }
    }
    S = waveSum(S); T = waveSum(T); U = waveSum(U); R = waveSum(R);
    if ((t & 63) == 0) { vfloat4 r = {S, T, U, R}; red4[t >> 6] = r; }
    __syncthreads();
    if (t == 0) {
        vfloat4 a = red4[0], b = red4[1], c = red4[2], d = red4[3];
        float Sf = (a.x + b.x) + (c.x + d.x);
        float Tf = (a.y + b.y) + (c.y + d.y);
        float Uf = (a.z + b.z) + (c.z + d.z);
        float Rf = (a.w + b.w) + (c.w + d.w);
        float lnS = logf(Sf);
        float negH = Tf / Sf - lnS
                   + EPSF * (Uf - (float)HW * lnS)
                   + (float)HW * EPSF
                   + 0.5f * EPSF * EPSF * Sf * Rf;
        ent[row] = -negH;
    }
}

// One block per (b,c) row. Inline stable top-k rank (jax.lax.top_k on
// importance=-entropy: smaller entropy wins; ties -> lower channel index),
// then copy row if kept else zero-fill. Nontemporal stores keep x resident
// in L3 (205.5 MB < 256 MB) so the kept-row re-read is an L3 hit.
__global__ __launch_bounds__(256) void apply_kernel(const float* __restrict__ x,
                                                    const float* __restrict__ ent,
                                                    float* __restrict__ out) {
    __shared__ int sred[4];
    __shared__ int skeep;
    const int row = blockIdx.x;
    const int b = row >> 8;        // row / CC
    const int c = row & (CC - 1);  // row % CC
    const int t = threadIdx.x;

    const float e_mine = ent[row];
    const float ej = ent[b * CC + t];
    int pred = (ej < e_mine) || (ej == e_mine && t < c);
    int wsum = waveSumI(pred);
    if ((t & 63) == 0) sred[t >> 6] = wsum;
    __syncthreads();
    if (t == 0) {
        int rank = (sred[0] + sred[1]) + (sred[2] + sred[3]);
        skeep = (rank < KSEL) ? 1 : 0;
    }
    __syncthreads();
    const int keep = skeep;

    const vfloat4* __restrict__ xr =
        reinterpret_cast<const vfloat4*>(x) + (size_t)row * NV4;
    vfloat4* __restrict__ orow = reinterpret_cast<vfloat4*>(out) + (size_t)row * NV4;
    if (keep) {
#pragma unroll
        for (int j = 0; j < 4; ++j) {
            int idx = t + j * 256;
            if (idx < NV4) __builtin_nontemporal_store(xr[idx], &orow[idx]);
        }
    } else {
        const vfloat4 z = {0.f, 0.f, 0.f, 0.f};
#pragma unroll
        for (int j = 0; j < 4; ++j) {
            int idx = t + j * 256;
            if (idx < NV4) __builtin_nontemporal_store(z, &orow[idx]);
        }
    }
}

extern "C" void kernel_launch(void* const* d_in, const int* in_sizes, int n_in,
                              void* d_out, int out_size, void* d_ws, size_t ws_size,
                              hipStream_t stream) {
    const float* x = (const float*)d_in[0];
    float* out = (float*)d_out;
    float* ent = (float*)d_ws;   // 64*256*4 = 64 KiB of ws

    ent_kernel<<<BB * CC, 256, 0, stream>>>(x, ent);
    apply_kernel<<<BB * CC, 256, 0, stream>>>(x, ent, out);
}